// Round 2
// baseline (80.185 us; speedup 1.0000x reference)
//
#include <hip/hip_runtime.h>
#include <math.h>

#define EPSF 1e-6f

__device__ __forceinline__ float sigmoidf_(float v) { return 1.0f / (1.0f + __expf(-v)); }

// ---------------- Kernel 1: ConvDeepSet encoder ----------------
// grid: (ceil(M/8), nb), block 1024 (128 n-groups x 8 m)
__global__ __launch_bounds__(1024) void enc_kernel(
    const float* __restrict__ x, const float* __restrict__ y,
    const float* __restrict__ xg, const float* __restrict__ enc_sigma,
    const float* __restrict__ gW, const float* __restrict__ gb,
    float* __restrict__ rep_s, int nb, int npts, int M)
{
    __shared__ float sx[6144];
    __shared__ float sy[6144];
    __shared__ float red[16][8][6];   // [wave][mi][c]
    __shared__ float tot[8][6];
    int b = blockIdx.y;
    int mt = blockIdx.x * 8;
    int tid = threadIdx.x;
    int n3 = npts * 3;
    // stage x,y for this batch into LDS (float4)
    {
        const float4* x4 = (const float4*)(x + (size_t)b * n3);
        const float4* y4 = (const float4*)(y + (size_t)b * n3);
        int n4 = n3 >> 2;
        for (int i = tid; i < n4; i += 1024) {
            ((float4*)sx)[i] = x4[i];
            ((float4*)sy)[i] = y4[i];
        }
        for (int i = (n4 << 2) + tid; i < n3; i += 1024) {  // tail (normally empty)
            sx[i] = x[(size_t)b * n3 + i];
            sy[i] = y[(size_t)b * n3 + i];
        }
    }
    int mi = tid & 7, ng = tid >> 3;
    int m = mt + mi;
    bool mv = (m < M);
    float inv_s[3], g[3];
    for (int c = 0; c < 3; c++) inv_s[c] = 1.0f / (__expf(enc_sigma[c]) + EPSF);
    for (int c = 0; c < 3; c++) g[c] = mv ? xg[(size_t)(b * M + m) * 3 + c] : 0.0f;
    __syncthreads();
    float h0[3] = {0, 0, 0}, h1[3] = {0, 0, 0};
    for (int n = ng; n < npts; n += 128) {
        const float* xp = sx + n * 3;
        const float* yp = sy + n * 3;
        for (int c = 0; c < 3; c++) {
            float d = (xp[c] - g[c]) * inv_s[c];
            float w = __expf(-0.5f * d * d);
            h0[c] += w;
            h1[c] = fmaf(yp[c], w, h1[c]);
        }
    }
    // butterfly over lane bits 3..5 -> sum across the 8 ng-groups in each wave
    for (int mask = 8; mask <= 32; mask <<= 1) {
        for (int c = 0; c < 3; c++) {
            h0[c] += __shfl_xor(h0[c], mask, 64);
            h1[c] += __shfl_xor(h1[c], mask, 64);
        }
    }
    int lane = tid & 63, wv = tid >> 6;
    if (lane < 8) {
        for (int c = 0; c < 3; c++) { red[wv][lane][c] = h0[c]; red[wv][lane][3 + c] = h1[c]; }
    }
    __syncthreads();
    if (tid < 48) {
        int mi2 = tid & 7, c2 = tid >> 3;
        float s = 0.0f;
        for (int k = 0; k < 16; k++) s += red[k][mi2][c2];
        tot[mi2][c2] = s;
    }
    __syncthreads();
    if (tid < 128) {
        int mi2 = tid & 7, j = tid >> 3;
        int m2 = mt + mi2;
        if (m2 < M) {
            float cat[6];
            for (int c = 0; c < 3; c++) {
                cat[c] = tot[mi2][c];
                cat[3 + c] = tot[mi2][3 + c] / (tot[mi2][c] + EPSF);
            }
            float r = gb[j];
            for (int i = 0; i < 6; i++) r = fmaf(cat[i], gW[i * 16 + j], r);
            rep_s[((size_t)b * 16 + j) * M + m2] = sigmoidf_(r);
        }
    }
}

// ---------------- Kernel 2: rho CNN (3 convs) + linear head ----------------
// grid: (ceil(M/8), nb), block 256; column tile = 8
__global__ void rho_kernel(const float* __restrict__ rep_s,
                           const float* __restrict__ w1, const float* __restrict__ b1,
                           const float* __restrict__ w2, const float* __restrict__ b2,
                           const float* __restrict__ w3, const float* __restrict__ b3,
                           const float* __restrict__ linW, const float* __restrict__ linb,
                           float* __restrict__ mu, float* __restrict__ stdv,
                           int nb, int M)
{
    __shared__ float sIn[16][20];   // input cols t0-6 .. t0+13
    __shared__ float sH1[32][16];   // cols t0-4 .. t0+11
    __shared__ float sH2[32][12];   // cols t0-2 .. t0+9
    __shared__ float sH3[32][8];    // cols t0   .. t0+7
    __shared__ float sW[5120];      // reused: w1 (2560), then w2, then w3 (5120)
    __shared__ float sLW[960];      // linW
    int b = blockIdx.y;
    int t0 = blockIdx.x * 8;
    int tid = threadIdx.x;
    // stage input tile + w1 + linW
    for (int idx = tid; idx < 16 * 20; idx += 256) {
        int i = idx / 20, q = idx % 20;
        int mg = t0 - 6 + q;
        sIn[i][q] = (mg >= 0 && mg < M) ? rep_s[((size_t)b * 16 + i) * M + mg] : 0.0f;
    }
    for (int idx = tid; idx < 2560; idx += 256) sW[idx] = w1[idx];
    for (int idx = tid; idx < 960; idx += 256) sLW[idx] = linW[idx];
    __syncthreads();
    int o = tid >> 3, q0 = tid & 7;
    // conv1: 16 output cols (global col = t0 - 4 + q)
    float c1a[2];
    for (int h = 0; h < 2; h++) {
        int q = q0 + 8 * h;
        float acc = b1[o];
        for (int i = 0; i < 16; i++) {
            const float* wp = sW + (o * 16 + i) * 5;
            for (int k = 0; k < 5; k++) acc = fmaf(sIn[i][q + k], wp[k], acc);
        }
        c1a[h] = acc;
    }
    __syncthreads();  // done reading sW (w1)
    for (int h = 0; h < 2; h++) {
        int q = q0 + 8 * h;
        int gc = t0 - 4 + q;
        sH1[o][q] = (gc >= 0 && gc < M) ? fmaxf(c1a[h], 0.0f) : 0.0f;
    }
    for (int idx = tid; idx < 5120; idx += 256) sW[idx] = w2[idx];
    __syncthreads();
    // conv2: 12 output cols (global col = t0 - 2 + q)
    float c2a[2]; int c2n = (q0 < 4) ? 2 : 1;
    for (int h = 0; h < c2n; h++) {
        int q = q0 + 8 * h;
        float acc = b2[o];
        for (int i = 0; i < 32; i++) {
            const float* wp = sW + (o * 32 + i) * 5;
            for (int k = 0; k < 5; k++) acc = fmaf(sH1[i][q + k], wp[k], acc);
        }
        c2a[h] = acc;
    }
    __syncthreads();  // done reading sW (w2)
    for (int h = 0; h < c2n; h++) {
        int q = q0 + 8 * h;
        int gc = t0 - 2 + q;
        sH2[o][q] = (gc >= 0 && gc < M) ? fmaxf(c2a[h], 0.0f) : 0.0f;
    }
    for (int idx = tid; idx < 5120; idx += 256) sW[idx] = w3[idx];
    __syncthreads();
    // conv3: 8 output cols (global col = t0 + q0), no relu
    {
        float acc = b3[o];
        for (int i = 0; i < 32; i++) {
            const float* wp = sW + (o * 32 + i) * 5;
            for (int k = 0; k < 5; k++) acc = fmaf(sH2[i][q0 + k], wp[k], acc);
        }
        sH3[o][q0] = acc;
    }
    __syncthreads();
    // head: h_grid = h^T @ linW + linb ; split mu / processed std
    for (int idx = tid; idx < 240; idx += 256) {
        int q = idx / 30, j = idx % 30;
        int m = t0 + q;
        if (m < M) {
            float v = linb[j];
            for (int oo = 0; oo < 32; oo++) v = fmaf(sH3[oo][q], sLW[oo * 30 + j], v);
            if (j < 15) mu[((size_t)b * M + m) * 15 + j] = v;
            else        stdv[((size_t)b * M + m) * 15 + (j - 15)] = 0.1f + 0.9f * sigmoidf_(v);
        }
    }
}

// ---------------- Kernel 3: FinalLayer interpolation + output head ----------------
// grid: (ceil(ntar/8), nb), block 256 (32 m-groups x 8 t)
__global__ void final_kernel(const float* __restrict__ x_out, const float* __restrict__ xg,
                             const float* __restrict__ int_sigma, const float* __restrict__ eps,
                             const float* __restrict__ mu, const float* __restrict__ stdv,
                             const float* __restrict__ loW, const float* __restrict__ lob,
                             float* __restrict__ out, int nb, int ntar, int M)
{
    __shared__ float red2[4][8][30];   // [wave][ti][A0..14,B0..14]
    __shared__ float AB[8][30];
    int b = blockIdx.y;
    int tt = blockIdx.x * 8;
    int tid = threadIdx.x;
    int ti = tid & 7, mg = tid >> 3;
    int t = tt + ti;
    bool tv = (t < ntar);
    float xt[3];
    for (int c = 0; c < 3; c++) xt[c] = tv ? x_out[((size_t)b * ntar + t) * 3 + c] : 0.0f;
    float inv_isc[15];
    for (int k = 0; k < 15; k++) inv_isc[k] = 1.0f / (__expf(int_sigma[k]) + EPSF);
    float A[15], B[15];
    for (int k = 0; k < 15; k++) { A[k] = 0.0f; B[k] = 0.0f; }
    for (int m = mg; m < M; m += 32) {
        const float* gp = xg + (size_t)(b * M + m) * 3;
        float gv[3] = {gp[0], gp[1], gp[2]};
        const float* mup = mu + ((size_t)b * M + m) * 15;
        const float* sdp = stdv + ((size_t)b * M + m) * 15;
        for (int k = 0; k < 15; k++) {
            int c = k % 3;  // k = basis*3 + c
            float d = (gv[c] - xt[c]) * inv_isc[k];
            float w = __expf(-0.5f * d * d);
            A[k] = fmaf(mup[k], w, A[k]);
            B[k] = fmaf(sdp[k], w, B[k]);
        }
    }
    // butterfly over lane bits 3..5 -> sum across the 8 mg-groups within each wave
    for (int mask = 8; mask <= 32; mask <<= 1) {
        for (int k = 0; k < 15; k++) {
            A[k] += __shfl_xor(A[k], mask, 64);
            B[k] += __shfl_xor(B[k], mask, 64);
        }
    }
    int lane = tid & 63, wv = tid >> 6;
    if (lane < 8) {
        for (int k = 0; k < 15; k++) { red2[wv][lane][k] = A[k]; red2[wv][lane][15 + k] = B[k]; }
    }
    __syncthreads();
    for (int idx = tid; idx < 240; idx += 256) {
        int t2 = idx / 30, v = idx % 30;
        AB[t2][v] = red2[0][t2][v] + red2[1][t2][v] + red2[2][t2][v] + red2[3][t2][v];
    }
    __syncthreads();
    // outputs: 8 t x 4 samples x 6 channels = 192
    if (tid < 192) {
        int t2 = tid / 24;
        int rem = tid % 24;
        int s = rem / 6, j = rem % 6;
        int tg = tt + t2;
        if (tg < ntar) {
            float val = lob[j];
            const float* ep = eps + ((size_t)s * nb + b) * 15;
            for (int k = 0; k < 15; k++) {
                float h = fmaf(ep[k], AB[t2][15 + k], AB[t2][k]);
                val = fmaf(h, loW[k * 6 + j], val);
            }
            if (j >= 3) val = fmaxf(val, 0.0f) + log1pf(__expf(-fabsf(val)));  // softplus
            out[(((size_t)s * nb + b) * ntar + tg) * 6 + j] = val;
        }
    }
}

extern "C" void kernel_launch(void* const* d_in, const int* in_sizes, int n_in,
                              void* d_out, int out_size, void* d_ws, size_t ws_size,
                              hipStream_t stream)
{
    const float* x         = (const float*)d_in[0];
    const float* y         = (const float*)d_in[1];
    const float* x_out     = (const float*)d_in[2];
    const float* x_grid    = (const float*)d_in[3];
    const float* eps_noise = (const float*)d_in[4];
    const float* enc_sigma = (const float*)d_in[5];
    const float* gW        = (const float*)d_in[6];
    const float* gb        = (const float*)d_in[7];
    const float* w1        = (const float*)d_in[8];
    const float* b1        = (const float*)d_in[9];
    const float* w2        = (const float*)d_in[10];
    const float* b2        = (const float*)d_in[11];
    const float* w3        = (const float*)d_in[12];
    const float* b3        = (const float*)d_in[13];
    const float* linW      = (const float*)d_in[14];
    const float* linb      = (const float*)d_in[15];
    const float* int_sigma = (const float*)d_in[16];
    const float* loW       = (const float*)d_in[17];
    const float* lob       = (const float*)d_in[18];
    float* out = (float*)d_out;

    const int NS = 4, C = 3, NBASIS = 5;
    int nb   = in_sizes[4] / (NS * C * NBASIS);       // eps_noise: (NS, nb, 15)
    int npts = in_sizes[0] / (nb * C);
    int ntar = in_sizes[2] / (nb * C);
    int M    = in_sizes[3] / (nb * C);

    float* rep_s = (float*)d_ws;                       // (nb, 16, M)
    float* mu    = rep_s + (size_t)nb * 16 * M;        // (nb, M, 15)
    float* stdv  = mu + (size_t)nb * M * 15;           // (nb, M, 15)

    enc_kernel<<<dim3((M + 7) / 8, nb), 1024, 0, stream>>>(
        x, y, x_grid, enc_sigma, gW, gb, rep_s, nb, npts, M);
    rho_kernel<<<dim3((M + 7) / 8, nb), 256, 0, stream>>>(
        rep_s, w1, b1, w2, b2, w3, b3, linW, linb, mu, stdv, nb, M);
    final_kernel<<<dim3((ntar + 7) / 8, nb), 256, 0, stream>>>(
        x_out, x_grid, int_sigma, eps_noise, mu, stdv, loW, lob, out, nb, ntar, M);
}

// Round 3
// 56.925 us; speedup vs baseline: 1.4086x; 1.4086x over previous
//
#include <hip/hip_runtime.h>
#include <math.h>

#define EPSF 1e-6f

__device__ __forceinline__ float sigmoidf_(float v) { return 1.0f / (1.0f + __expf(-v)); }

// ---------------- Kernel 1: ConvDeepSet encoder ----------------
// grid: (ceil(M/8), nb), block 1024 (128 n-groups x 8 m)
__global__ __launch_bounds__(1024) void enc_kernel(
    const float* __restrict__ x, const float* __restrict__ y,
    const float* __restrict__ xg, const float* __restrict__ enc_sigma,
    const float* __restrict__ gW, const float* __restrict__ gb,
    float* __restrict__ rep_s, int nb, int npts, int M)
{
    __shared__ float sx[6144];
    __shared__ float sy[6144];
    __shared__ float red[16][8][6];   // [wave][mi][c]
    __shared__ float tot[8][6];
    int b = blockIdx.y;
    int mt = blockIdx.x * 8;
    int tid = threadIdx.x;
    int n3 = npts * 3;
    // stage x,y for this batch into LDS (float4)
    {
        const float4* x4 = (const float4*)(x + (size_t)b * n3);
        const float4* y4 = (const float4*)(y + (size_t)b * n3);
        int n4 = n3 >> 2;
        for (int i = tid; i < n4; i += 1024) {
            ((float4*)sx)[i] = x4[i];
            ((float4*)sy)[i] = y4[i];
        }
        for (int i = (n4 << 2) + tid; i < n3; i += 1024) {  // tail (normally empty)
            sx[i] = x[(size_t)b * n3 + i];
            sy[i] = y[(size_t)b * n3 + i];
        }
    }
    int mi = tid & 7, ng = tid >> 3;
    int m = mt + mi;
    bool mv = (m < M);
    float inv_s[3], g[3];
    for (int c = 0; c < 3; c++) inv_s[c] = 1.0f / (__expf(enc_sigma[c]) + EPSF);
    for (int c = 0; c < 3; c++) g[c] = mv ? xg[(size_t)(b * M + m) * 3 + c] : 0.0f;
    __syncthreads();
    float h0[3] = {0, 0, 0}, h1[3] = {0, 0, 0};
    for (int n = ng; n < npts; n += 128) {
        const float* xp = sx + n * 3;
        const float* yp = sy + n * 3;
        for (int c = 0; c < 3; c++) {
            float d = (xp[c] - g[c]) * inv_s[c];
            float w = __expf(-0.5f * d * d);
            h0[c] += w;
            h1[c] = fmaf(yp[c], w, h1[c]);
        }
    }
    // butterfly over lane bits 3..5 -> sum across the 8 ng-groups in each wave
    for (int mask = 8; mask <= 32; mask <<= 1) {
        for (int c = 0; c < 3; c++) {
            h0[c] += __shfl_xor(h0[c], mask, 64);
            h1[c] += __shfl_xor(h1[c], mask, 64);
        }
    }
    int lane = tid & 63, wv = tid >> 6;
    if (lane < 8) {
        for (int c = 0; c < 3; c++) { red[wv][lane][c] = h0[c]; red[wv][lane][3 + c] = h1[c]; }
    }
    __syncthreads();
    if (tid < 48) {
        int mi2 = tid & 7, c2 = tid >> 3;
        float s = 0.0f;
        for (int k = 0; k < 16; k++) s += red[k][mi2][c2];
        tot[mi2][c2] = s;
    }
    __syncthreads();
    if (tid < 128) {
        int mi2 = tid & 7, j = tid >> 3;
        int m2 = mt + mi2;
        if (m2 < M) {
            float cat[6];
            for (int c = 0; c < 3; c++) {
                cat[c] = tot[mi2][c];
                cat[3 + c] = tot[mi2][3 + c] / (tot[mi2][c] + EPSF);
            }
            float r = gb[j];
            for (int i = 0; i < 6; i++) r = fmaf(cat[i], gW[i * 16 + j], r);
            rep_s[((size_t)b * 16 + j) * M + m2] = sigmoidf_(r);
        }
    }
}

// ---------------- Kernel 2: rho CNN (3 convs) + linear head ----------------
// grid: (ceil(M/16), nb), block 256; column tile = 16
// LDS: sWA (w1 then w3), sWB (w2), tiles. linW read direct from global (L1-hot).
__global__ __launch_bounds__(256) void rho_kernel(
    const float* __restrict__ rep_s,
    const float* __restrict__ w1, const float* __restrict__ b1,
    const float* __restrict__ w2, const float* __restrict__ b2,
    const float* __restrict__ w3, const float* __restrict__ b3,
    const float* __restrict__ linW, const float* __restrict__ linb,
    float* __restrict__ mu, float* __restrict__ stdv,
    int nb, int M)
{
    __shared__ float sWA[5120];     // w1 (2560 used), later w3 (5120)
    __shared__ float sWB[5120];     // w2
    __shared__ float sIn[16][28];   // input cols t0-6 .. t0+21
    __shared__ float sH1[32][24];   // cols t0-4 .. t0+19
    __shared__ float sH2[32][20];   // cols t0-2 .. t0+17
    __shared__ float sH3[32][16];   // cols t0   .. t0+15
    int b = blockIdx.y;
    int t0 = blockIdx.x * 16;
    int tid = threadIdx.x;
    // ---- stage w1, w2 (float4) + input tile; single barrier ----
    {
        const float4* w1v = (const float4*)w1;   // 640
        const float4* w2v = (const float4*)w2;   // 1280
        for (int idx = tid; idx < 640; idx += 256) ((float4*)sWA)[idx] = w1v[idx];
        for (int h = 0; h < 5; h++) ((float4*)sWB)[tid + 256 * h] = w2v[tid + 256 * h];
        for (int idx = tid; idx < 16 * 28; idx += 256) {
            int i = idx / 28, q = idx % 28;
            int mg = t0 - 6 + q;
            sIn[i][q] = (mg >= 0 && mg < M) ? rep_s[((size_t)b * 16 + i) * M + mg] : 0.0f;
        }
    }
    __syncthreads();
    int o = tid >> 3, q0 = tid & 7;
    // ---- conv1: 24 out cols, 3 per thread (q0, q0+8, q0+16) ----
    {
        float a0 = b1[o], a1 = a0, a2 = a0;
        for (int i = 0; i < 16; i++) {
            const float* wp = sWA + (o * 16 + i) * 5;
            float w0 = wp[0], w1r = wp[1], w2r = wp[2], w3r = wp[3], w4 = wp[4];
            const float* ip = &sIn[i][0];
            a0 = fmaf(ip[q0], w0, a0);      a0 = fmaf(ip[q0+1], w1r, a0);
            a0 = fmaf(ip[q0+2], w2r, a0);   a0 = fmaf(ip[q0+3], w3r, a0);
            a0 = fmaf(ip[q0+4], w4, a0);
            a1 = fmaf(ip[q0+8], w0, a1);    a1 = fmaf(ip[q0+9], w1r, a1);
            a1 = fmaf(ip[q0+10], w2r, a1);  a1 = fmaf(ip[q0+11], w3r, a1);
            a1 = fmaf(ip[q0+12], w4, a1);
            a2 = fmaf(ip[q0+16], w0, a2);   a2 = fmaf(ip[q0+17], w1r, a2);
            a2 = fmaf(ip[q0+18], w2r, a2);  a2 = fmaf(ip[q0+19], w3r, a2);
            a2 = fmaf(ip[q0+20], w4, a2);
        }
        int g0 = t0 - 4 + q0, g1 = g0 + 8, g2 = g0 + 16;
        sH1[o][q0]      = (g0 >= 0 && g0 < M) ? fmaxf(a0, 0.0f) : 0.0f;
        sH1[o][q0 + 8]  = (g1 >= 0 && g1 < M) ? fmaxf(a1, 0.0f) : 0.0f;
        sH1[o][q0 + 16] = (g2 >= 0 && g2 < M) ? fmaxf(a2, 0.0f) : 0.0f;
    }
    __syncthreads();   // all conv1 (w1) reads done; sH1 ready
    // ---- issue w3 loads early (T14): global->regs; write to LDS after conv2 ----
    float4 wreg[5];
    {
        const float4* w3v = (const float4*)w3;   // 1280
        for (int h = 0; h < 5; h++) wreg[h] = w3v[tid + 256 * h];
    }
    // ---- conv2: 20 out cols, q0,q0+8 (+q0+16 if q0<4) ----
    {
        float a0 = b2[o], a1 = a0, a2 = a0;
        bool third = (q0 < 4);
        for (int i = 0; i < 32; i++) {
            const float* wp = sWB + (o * 32 + i) * 5;
            float w0 = wp[0], w1r = wp[1], w2r = wp[2], w3r = wp[3], w4 = wp[4];
            const float* ip = &sH1[i][0];
            a0 = fmaf(ip[q0], w0, a0);      a0 = fmaf(ip[q0+1], w1r, a0);
            a0 = fmaf(ip[q0+2], w2r, a0);   a0 = fmaf(ip[q0+3], w3r, a0);
            a0 = fmaf(ip[q0+4], w4, a0);
            a1 = fmaf(ip[q0+8], w0, a1);    a1 = fmaf(ip[q0+9], w1r, a1);
            a1 = fmaf(ip[q0+10], w2r, a1);  a1 = fmaf(ip[q0+11], w3r, a1);
            a1 = fmaf(ip[q0+12], w4, a1);
            if (third) {
                a2 = fmaf(ip[q0+16], w0, a2);   a2 = fmaf(ip[q0+17], w1r, a2);
                a2 = fmaf(ip[q0+18], w2r, a2);  a2 = fmaf(ip[q0+19], w3r, a2);
                a2 = fmaf(ip[q0+20], w4, a2);
            }
        }
        int g0 = t0 - 2 + q0, g1 = g0 + 8, g2 = g0 + 16;
        sH2[o][q0]     = (g0 >= 0 && g0 < M) ? fmaxf(a0, 0.0f) : 0.0f;
        sH2[o][q0 + 8] = (g1 >= 0 && g1 < M) ? fmaxf(a1, 0.0f) : 0.0f;
        if (third) sH2[o][q0 + 16] = (g2 >= 0 && g2 < M) ? fmaxf(a2, 0.0f) : 0.0f;
    }
    // write staged w3 into sWA (conv1 readers all passed the barrier above)
    for (int h = 0; h < 5; h++) ((float4*)sWA)[tid + 256 * h] = wreg[h];
    __syncthreads();   // sH2 + w3 ready
    // ---- conv3: 16 out cols, q0,q0+8; no relu ----
    {
        float a0 = b3[o], a1 = a0;
        for (int i = 0; i < 32; i++) {
            const float* wp = sWA + (o * 32 + i) * 5;
            float w0 = wp[0], w1r = wp[1], w2r = wp[2], w3r = wp[3], w4 = wp[4];
            const float* ip = &sH2[i][0];
            a0 = fmaf(ip[q0], w0, a0);      a0 = fmaf(ip[q0+1], w1r, a0);
            a0 = fmaf(ip[q0+2], w2r, a0);   a0 = fmaf(ip[q0+3], w3r, a0);
            a0 = fmaf(ip[q0+4], w4, a0);
            a1 = fmaf(ip[q0+8], w0, a1);    a1 = fmaf(ip[q0+9], w1r, a1);
            a1 = fmaf(ip[q0+10], w2r, a1);  a1 = fmaf(ip[q0+11], w3r, a1);
            a1 = fmaf(ip[q0+12], w4, a1);
        }
        sH3[o][q0] = a0;
        sH3[o][q0 + 8] = a1;
    }
    __syncthreads();
    // ---- head: 16 cols x 30 outs = 480; linW direct from global (L1-hot) ----
    for (int idx = tid; idx < 480; idx += 256) {
        int q = idx / 30, j = idx % 30;
        int m = t0 + q;
        if (m < M) {
            float v = linb[j];
            for (int oo = 0; oo < 32; oo++) v = fmaf(sH3[oo][q], linW[oo * 30 + j], v);
            if (j < 15) mu[((size_t)b * M + m) * 16 + j] = v;
            else        stdv[((size_t)b * M + m) * 16 + (j - 15)] = 0.1f + 0.9f * sigmoidf_(v);
        }
    }
}

// ---------------- Kernel 3: FinalLayer interpolation + output head ----------------
// grid: (ceil(ntar/8), nb), block 256 (32 m-groups x 8 t); mu/stdv row stride 16 (aligned)
__global__ void final_kernel(const float* __restrict__ x_out, const float* __restrict__ xg,
                             const float* __restrict__ int_sigma, const float* __restrict__ eps,
                             const float* __restrict__ mu, const float* __restrict__ stdv,
                             const float* __restrict__ loW, const float* __restrict__ lob,
                             float* __restrict__ out, int nb, int ntar, int M)
{
    __shared__ float red2[4][8][30];   // [wave][ti][A0..14,B0..14]
    __shared__ float AB[8][30];
    int b = blockIdx.y;
    int tt = blockIdx.x * 8;
    int tid = threadIdx.x;
    int ti = tid & 7, mg = tid >> 3;
    int t = tt + ti;
    bool tv = (t < ntar);
    float xt[3];
    for (int c = 0; c < 3; c++) xt[c] = tv ? x_out[((size_t)b * ntar + t) * 3 + c] : 0.0f;
    float inv_isc[15];
    for (int k = 0; k < 15; k++) inv_isc[k] = 1.0f / (__expf(int_sigma[k]) + EPSF);
    float A[15], B[15];
    for (int k = 0; k < 15; k++) { A[k] = 0.0f; B[k] = 0.0f; }
    for (int m = mg; m < M; m += 32) {
        const float* gp = xg + (size_t)(b * M + m) * 3;
        float gv[3] = {gp[0], gp[1], gp[2]};
        const float* mup = mu + ((size_t)b * M + m) * 16;
        const float* sdp = stdv + ((size_t)b * M + m) * 16;
        float mv[15], sv[15];
        {
            float4 a0 = *(const float4*)(mup), a1 = *(const float4*)(mup + 4),
                   a2 = *(const float4*)(mup + 8);
            float4 s0 = *(const float4*)(sdp), s1 = *(const float4*)(sdp + 4),
                   s2 = *(const float4*)(sdp + 8);
            mv[0]=a0.x; mv[1]=a0.y; mv[2]=a0.z; mv[3]=a0.w;
            mv[4]=a1.x; mv[5]=a1.y; mv[6]=a1.z; mv[7]=a1.w;
            mv[8]=a2.x; mv[9]=a2.y; mv[10]=a2.z; mv[11]=a2.w;
            mv[12]=mup[12]; mv[13]=mup[13]; mv[14]=mup[14];
            sv[0]=s0.x; sv[1]=s0.y; sv[2]=s0.z; sv[3]=s0.w;
            sv[4]=s1.x; sv[5]=s1.y; sv[6]=s1.z; sv[7]=s1.w;
            sv[8]=s2.x; sv[9]=s2.y; sv[10]=s2.z; sv[11]=s2.w;
            sv[12]=sdp[12]; sv[13]=sdp[13]; sv[14]=sdp[14];
        }
        #pragma unroll
        for (int k = 0; k < 15; k++) {
            int c = k % 3;  // k = basis*3 + c
            float d = (gv[c] - xt[c]) * inv_isc[k];
            float w = __expf(-0.5f * d * d);
            A[k] = fmaf(mv[k], w, A[k]);
            B[k] = fmaf(sv[k], w, B[k]);
        }
    }
    // butterfly over lane bits 3..5 -> sum across the 8 mg-groups within each wave
    for (int mask = 8; mask <= 32; mask <<= 1) {
        for (int k = 0; k < 15; k++) {
            A[k] += __shfl_xor(A[k], mask, 64);
            B[k] += __shfl_xor(B[k], mask, 64);
        }
    }
    int lane = tid & 63, wv = tid >> 6;
    if (lane < 8) {
        for (int k = 0; k < 15; k++) { red2[wv][lane][k] = A[k]; red2[wv][lane][15 + k] = B[k]; }
    }
    __syncthreads();
    for (int idx = tid; idx < 240; idx += 256) {
        int t2 = idx / 30, v = idx % 30;
        AB[t2][v] = red2[0][t2][v] + red2[1][t2][v] + red2[2][t2][v] + red2[3][t2][v];
    }
    __syncthreads();
    // outputs: 8 t x 4 samples x 6 channels = 192
    if (tid < 192) {
        int t2 = tid / 24;
        int rem = tid % 24;
        int s = rem / 6, j = rem % 6;
        int tg = tt + t2;
        if (tg < ntar) {
            float val = lob[j];
            const float* ep = eps + ((size_t)s * nb + b) * 15;
            for (int k = 0; k < 15; k++) {
                float h = fmaf(ep[k], AB[t2][15 + k], AB[t2][k]);
                val = fmaf(h, loW[k * 6 + j], val);
            }
            if (j >= 3) val = fmaxf(val, 0.0f) + log1pf(__expf(-fabsf(val)));  // softplus
            out[(((size_t)s * nb + b) * ntar + tg) * 6 + j] = val;
        }
    }
}

extern "C" void kernel_launch(void* const* d_in, const int* in_sizes, int n_in,
                              void* d_out, int out_size, void* d_ws, size_t ws_size,
                              hipStream_t stream)
{
    const float* x         = (const float*)d_in[0];
    const float* y         = (const float*)d_in[1];
    const float* x_out     = (const float*)d_in[2];
    const float* x_grid    = (const float*)d_in[3];
    const float* eps_noise = (const float*)d_in[4];
    const float* enc_sigma = (const float*)d_in[5];
    const float* gW        = (const float*)d_in[6];
    const float* gb        = (const float*)d_in[7];
    const float* w1        = (const float*)d_in[8];
    const float* b1        = (const float*)d_in[9];
    const float* w2        = (const float*)d_in[10];
    const float* b2        = (const float*)d_in[11];
    const float* w3        = (const float*)d_in[12];
    const float* b3        = (const float*)d_in[13];
    const float* linW      = (const float*)d_in[14];
    const float* linb      = (const float*)d_in[15];
    const float* int_sigma = (const float*)d_in[16];
    const float* loW       = (const float*)d_in[17];
    const float* lob       = (const float*)d_in[18];
    float* out = (float*)d_out;

    const int NS = 4, C = 3, NBASIS = 5;
    int nb   = in_sizes[4] / (NS * C * NBASIS);       // eps_noise: (NS, nb, 15)
    int npts = in_sizes[0] / (nb * C);
    int ntar = in_sizes[2] / (nb * C);
    int M    = in_sizes[3] / (nb * C);

    float* rep_s = (float*)d_ws;                       // (nb, 16, M)
    float* mu    = rep_s + (size_t)nb * 16 * M;        // (nb, M, 16)  row stride 16
    float* stdv  = mu + (size_t)nb * M * 16;           // (nb, M, 16)

    enc_kernel<<<dim3((M + 7) / 8, nb), 1024, 0, stream>>>(
        x, y, x_grid, enc_sigma, gW, gb, rep_s, nb, npts, M);
    rho_kernel<<<dim3((M + 15) / 16, nb), 256, 0, stream>>>(
        rep_s, w1, b1, w2, b2, w3, b3, linW, linb, mu, stdv, nb, M);
    final_kernel<<<dim3((ntar + 7) / 8, nb), 256, 0, stream>>>(
        x_out, x_grid, int_sigma, eps_noise, mu, stdv, loW, lob, out, nb, ntar, M);
}